// Round 1
// baseline (718.105 us; speedup 1.0000x reference)
//
#include <hip/hip_runtime.h>
#include <stdint.h>

// ---------------------------------------------------------------------------
// OrthoLinear: out[b,s,o] = sum_k x[b,s,k] * (dequant(base_packed,scales)[o,k]
//                                             + w_ortho[o,k])
// M = B*S = 8192, N = OUT = 4096, K = IN = 4096, fp32 in/out.
// Strategy: prep (x -> bf16, W -> bf16 fused dequant+residual) into d_ws,
// then m97-structure bf16 MFMA GEMM (128x128 tile, BK=32, global_load_lds w=16).
// ---------------------------------------------------------------------------

#define M_TOTAL 8192
#define N_TOTAL 4096
#define K_TOTAL 4096

typedef __attribute__((ext_vector_type(8)))  __bf16          bf16x8;   // MFMA A/B frag (4 VGPRs)
typedef __attribute__((ext_vector_type(4)))  float           floatx4;  // MFMA C/D frag
typedef __attribute__((ext_vector_type(8)))  unsigned short  ushort8;
typedef __attribute__((ext_vector_type(4)))  float           f32x4;
typedef __attribute__((ext_vector_type(4)))  int             intx4;

// fp32 -> bf16 round-to-nearest-even (data has no NaN)
__device__ __forceinline__ unsigned short f2bf(float f) {
    union { float f; uint32_t u; } c; c.f = f;
    uint32_t u = c.u + 0x7FFFu + ((c.u >> 16) & 1u);
    return (unsigned short)(u >> 16);
}

// ---------------------------------------------------------------------------
// Prep 1: x fp32 [M,K] -> bf16 [M,K].  8 floats / thread.
// ---------------------------------------------------------------------------
__global__ __launch_bounds__(256) void cvt_x_kernel(const float* __restrict__ x,
                                                    unsigned short* __restrict__ xb) {
    const size_t t = (size_t)blockIdx.x * 256 + threadIdx.x;
    const f32x4* xv = (const f32x4*)x;
    f32x4 v0 = xv[2 * t];
    f32x4 v1 = xv[2 * t + 1];
    ushort8 r;
    r[0] = f2bf(v0[0]); r[1] = f2bf(v0[1]); r[2] = f2bf(v0[2]); r[3] = f2bf(v0[3]);
    r[4] = f2bf(v1[0]); r[5] = f2bf(v1[1]); r[6] = f2bf(v1[2]); r[7] = f2bf(v1[3]);
    ((ushort8*)xb)[t] = r;
}

// ---------------------------------------------------------------------------
// Prep 2: W[o,k] = (nibble(base_packed)-8)*scale[o] + w_ortho[o,k] -> bf16 [N,K]
// One thread: 4 packed int32 (= 8 weights). Low nibble = even k, high = odd k.
// ---------------------------------------------------------------------------
__global__ __launch_bounds__(256) void dequant_w_kernel(
    const int*   __restrict__ packed,   // [N, K/2] values in [0,256)
    const float* __restrict__ scales,   // [N]
    const float* __restrict__ ortho,    // [N, K] dense (~5% nnz), alpha = 1.0
    unsigned short* __restrict__ wb)    // [N, K] bf16 out
{
    const int t  = blockIdx.x * 256 + threadIdx.x;       // 0 .. N*(K/2)/4
    const int o  = t >> 9;                               // 512 threads per row
    const int jp = (t & 511) << 2;                       // packed col base
    intx4 p = *(const intx4*)(packed + (size_t)o * (K_TOTAL / 2) + jp);
    const float s = scales[o];
    const size_t base = (size_t)o * K_TOTAL + (size_t)jp * 2;
    f32x4 g0 = *(const f32x4*)(ortho + base);
    f32x4 g1 = *(const f32x4*)(ortho + base + 4);
    float g[8] = { g0[0], g0[1], g0[2], g0[3], g1[0], g1[1], g1[2], g1[3] };
    ushort8 r;
#pragma unroll
    for (int i = 0; i < 4; ++i) {
        int pi = p[i];
        float lo = (float)((pi & 0xF) - 8) * s + g[2 * i];
        float hi = (float)(((pi >> 4) & 0xF) - 8) * s + g[2 * i + 1];
        r[2 * i]     = f2bf(lo);
        r[2 * i + 1] = f2bf(hi);
    }
    *(ushort8*)(wb + base) = r;
}

// ---------------------------------------------------------------------------
// GEMM: C[M,N] = A[M,K](bf16) @ B[N,K](bf16)^T, fp32 accumulate.
// m97 structure: 128x128 block tile, BK=32, 256 threads = 4 waves (2x2 of
// 64x64), 4x4 mfma_f32_16x16x32_bf16 per wave, global_load_lds width 16.
// ---------------------------------------------------------------------------
__device__ __forceinline__ void async16(const void* g, void* l) {
    __builtin_amdgcn_global_load_lds(
        (__attribute__((address_space(1))) void*)(g),
        (__attribute__((address_space(3))) void*)(l),
        16, 0, 0);
}

__global__ __launch_bounds__(256) void gemm_bt_kernel(
    const unsigned short* __restrict__ A,   // [M,K] bf16
    const unsigned short* __restrict__ Bm,  // [N,K] bf16
    float* __restrict__ C)                  // [M,N] fp32
{
    // LDS tiles: no padding — global_load_lds dest is wave-uniform base + lane*16,
    // layout must be the exact row-major order the staging lanes produce.
    __shared__ __attribute__((aligned(16))) unsigned short As[128 * 32]; // 8 KB
    __shared__ __attribute__((aligned(16))) unsigned short Bs[128 * 32]; // 8 KB

    const int tid  = threadIdx.x;
    const int wave = tid >> 6;
    const int lane = tid & 63;
    const int quad = lane >> 4;
    const int r16  = lane & 15;

    const int row0 = blockIdx.y * 128;   // M origin
    const int col0 = blockIdx.x * 128;   // N origin
    const int m_off = (wave >> 1) * 64;  // wave sub-tile in M
    const int n_off = (wave & 1) * 64;   // wave sub-tile in N

    // Staging map: round j in {0,1}; thread t covers tile row j*64 + t/4,
    // cols (t%4)*8 .. +8 (16 B). LDS byte offset = j*4096 + t*16.
    const int sr = tid >> 2;        // 0..63
    const int sc = (tid & 3) * 8;   // 0,8,16,24

    const unsigned short* Ag0 = A  + (size_t)(row0 + sr)      * K_TOTAL + sc;
    const unsigned short* Ag1 = A  + (size_t)(row0 + 64 + sr) * K_TOTAL + sc;
    const unsigned short* Bg0 = Bm + (size_t)(col0 + sr)      * K_TOTAL + sc;
    const unsigned short* Bg1 = Bm + (size_t)(col0 + 64 + sr) * K_TOTAL + sc;

    unsigned short* AsD0 = As + wave * 512;          // bytes: wave*1024
    unsigned short* AsD1 = As + 2048 + wave * 512;   // bytes: 4096 + wave*1024
    unsigned short* BsD0 = Bs + wave * 512;
    unsigned short* BsD1 = Bs + 2048 + wave * 512;

    // Fragment LDS element offsets (row stride = 32 elems = 64 B; quad*8 -> 16 B aligned)
    const int a_ofs = (m_off + r16) * 32 + quad * 8;
    const int b_ofs = (n_off + r16) * 32 + quad * 8;

    floatx4 acc[4][4] = {};

    for (int kt = 0; kt < K_TOTAL; kt += 32) {
        __syncthreads();                 // previous iter's readers done
        async16(Ag0 + kt, AsD0);
        async16(Ag1 + kt, AsD1);
        async16(Bg0 + kt, BsD0);
        async16(Bg1 + kt, BsD1);
        __syncthreads();                 // compiler drains vmcnt(0) before s_barrier

        bf16x8 a[4], b[4];
#pragma unroll
        for (int i = 0; i < 4; ++i)
            a[i] = *(const bf16x8*)(As + a_ofs + i * (16 * 32));
#pragma unroll
        for (int i = 0; i < 4; ++i)
            b[i] = *(const bf16x8*)(Bs + b_ofs + i * (16 * 32));

#pragma unroll
        for (int mi = 0; mi < 4; ++mi)
#pragma unroll
            for (int ni = 0; ni < 4; ++ni)
                acc[mi][ni] = __builtin_amdgcn_mfma_f32_16x16x32_bf16(
                    a[mi], b[ni], acc[mi][ni], 0, 0, 0);
    }

    // Epilogue. C/D layout (m89/m91-verified): col = lane&15, row = quad*4 + reg.
#pragma unroll
    for (int mi = 0; mi < 4; ++mi) {
#pragma unroll
        for (int ni = 0; ni < 4; ++ni) {
            const int r = row0 + m_off + mi * 16 + quad * 4;
            const int c = col0 + n_off + ni * 16 + r16;
#pragma unroll
            for (int i = 0; i < 4; ++i)
                C[(size_t)(r + i) * N_TOTAL + c] = acc[mi][ni][i];
        }
    }
}

// ---------------------------------------------------------------------------
extern "C" void kernel_launch(void* const* d_in, const int* in_sizes, int n_in,
                              void* d_out, int out_size, void* d_ws, size_t ws_size,
                              hipStream_t stream) {
    const float* x      = (const float*)d_in[0];   // [4,2048,4096] fp32
    const int*   packed = (const int*)d_in[1];     // [4096,2048] int32
    const float* scales = (const float*)d_in[2];   // [4096,1] fp32
    const float* ortho  = (const float*)d_in[3];   // [4096,4096] fp32
    float*       out    = (float*)d_out;           // [4,2048,4096] fp32

    // Workspace layout: Xb (bf16, 64 MB) | Wb (bf16, 32 MB) = 96 MB total
    unsigned short* Xb = (unsigned short*)d_ws;
    unsigned short* Wb = (unsigned short*)((char*)d_ws + (size_t)M_TOTAL * K_TOTAL * 2);

    // x -> bf16: 8192*4096/8 threads = 4,194,304 -> 16384 blocks
    cvt_x_kernel<<<16384, 256, 0, stream>>>(x, Xb);
    // W dequant+residual -> bf16: 4096*2048/4 threads = 2,097,152 -> 8192 blocks
    dequant_w_kernel<<<8192, 256, 0, stream>>>(packed, scales, ortho, Wb);

    dim3 grid(N_TOTAL / 128, M_TOTAL / 128);  // (32, 64) = 2048 blocks
    gemm_bt_kernel<<<grid, 256, 0, stream>>>(Xb, Wb, out);
}

// Round 2
// 638.395 us; speedup vs baseline: 1.1249x; 1.1249x over previous
//
#include <hip/hip_runtime.h>
#include <stdint.h>

// ---------------------------------------------------------------------------
// OrthoLinear: out[b,s,o] = sum_k x[b,s,k] * (dequant(base_packed,scales)[o,k]
//                                             + w_ortho[o,k])
// M = B*S = 8192, N = OUT = 4096, K = IN = 4096, fp32 in/out.
// R2: BK=64 GEMM (2x BK=32 sub-tiles per barrier pair -> half the barrier
// drains, same verified LDS addressing), merged prep kernel (1 dispatch).
// ---------------------------------------------------------------------------

#define M_TOTAL 8192
#define N_TOTAL 4096
#define K_TOTAL 4096

typedef __attribute__((ext_vector_type(8)))  __bf16          bf16x8;   // MFMA A/B frag (4 VGPRs)
typedef __attribute__((ext_vector_type(4)))  float           floatx4;  // MFMA C/D frag
typedef __attribute__((ext_vector_type(8)))  unsigned short  ushort8;
typedef __attribute__((ext_vector_type(4)))  float           f32x4;
typedef __attribute__((ext_vector_type(4)))  int             intx4;

// fp32 -> bf16 round-to-nearest-even (data has no NaN)
__device__ __forceinline__ unsigned short f2bf(float f) {
    union { float f; uint32_t u; } c; c.f = f;
    uint32_t u = c.u + 0x7FFFu + ((c.u >> 16) & 1u);
    return (unsigned short)(u >> 16);
}

// ---------------------------------------------------------------------------
// Merged prep: blocks [0, 16384) convert x fp32->bf16 (8 floats/thread);
// blocks [16384, 24576) dequant W: (nibble-8)*scale + ortho -> bf16.
// Branch is block-uniform -> no divergence inside a wave.
// ---------------------------------------------------------------------------
#define CVT_BLOCKS 16384
#define DEQ_BLOCKS 8192

__global__ __launch_bounds__(256) void prep_kernel(
    const float* __restrict__ x,        // [M, K] fp32
    const int*   __restrict__ packed,   // [N, K/2] nibble-packed
    const float* __restrict__ scales,   // [N]
    const float* __restrict__ ortho,    // [N, K] fp32
    unsigned short* __restrict__ xb,    // [M, K] bf16 out
    unsigned short* __restrict__ wb)    // [N, K] bf16 out
{
    const int blk = blockIdx.x;
    if (blk < CVT_BLOCKS) {
        const size_t t = (size_t)blk * 256 + threadIdx.x;
        const f32x4* xv = (const f32x4*)x;
        f32x4 v0 = xv[2 * t];
        f32x4 v1 = xv[2 * t + 1];
        ushort8 r;
        r[0] = f2bf(v0[0]); r[1] = f2bf(v0[1]); r[2] = f2bf(v0[2]); r[3] = f2bf(v0[3]);
        r[4] = f2bf(v1[0]); r[5] = f2bf(v1[1]); r[6] = f2bf(v1[2]); r[7] = f2bf(v1[3]);
        ((ushort8*)xb)[t] = r;
    } else {
        const int t  = (blk - CVT_BLOCKS) * 256 + threadIdx.x;  // 0 .. N*(K/2)/4
        const int o  = t >> 9;                                  // 512 threads/row
        const int jp = (t & 511) << 2;                          // packed col base
        intx4 p = *(const intx4*)(packed + (size_t)o * (K_TOTAL / 2) + jp);
        const float s = scales[o];
        const size_t base = (size_t)o * K_TOTAL + (size_t)jp * 2;
        f32x4 g0 = *(const f32x4*)(ortho + base);
        f32x4 g1 = *(const f32x4*)(ortho + base + 4);
        float g[8] = { g0[0], g0[1], g0[2], g0[3], g1[0], g1[1], g1[2], g1[3] };
        ushort8 r;
#pragma unroll
        for (int i = 0; i < 4; ++i) {
            int pi = p[i];
            float lo = (float)((pi & 0xF) - 8) * s + g[2 * i];
            float hi = (float)(((pi >> 4) & 0xF) - 8) * s + g[2 * i + 1];
            r[2 * i]     = f2bf(lo);
            r[2 * i + 1] = f2bf(hi);
        }
        *(ushort8*)(wb + base) = r;
    }
}

// ---------------------------------------------------------------------------
// GEMM: C[M,N] = A[M,K](bf16) @ B[N,K](bf16)^T, fp32 accumulate.
// 128x128 block tile, BK=64 (two BK=32 sub-tiles per barrier pair), 256
// threads = 4 waves (2x2 of 64x64), 4x4 mfma_f32_16x16x32_bf16 per k-step.
// LDS layout per matrix: [half h][128 rows][32 cols] -- each half identical
// to the verified BK=32 layout (keeps the ds_read bank pattern unchanged).
// ---------------------------------------------------------------------------
__device__ __forceinline__ void async16(const void* g, void* l) {
    __builtin_amdgcn_global_load_lds(
        (__attribute__((address_space(1))) void*)(g),
        (__attribute__((address_space(3))) void*)(l),
        16, 0, 0);
}

__global__ __launch_bounds__(256) void gemm_bt_kernel(
    const unsigned short* __restrict__ A,   // [M,K] bf16
    const unsigned short* __restrict__ Bm,  // [N,K] bf16
    float* __restrict__ C)                  // [M,N] fp32
{
    // 2 halves x 128 rows x 32 cols each = 8192 elems (16 KB) per matrix.
    __shared__ __attribute__((aligned(16))) unsigned short As[2 * 128 * 32];
    __shared__ __attribute__((aligned(16))) unsigned short Bs[2 * 128 * 32];

    const int tid  = threadIdx.x;
    const int wave = tid >> 6;
    const int lane = tid & 63;
    const int quad = lane >> 4;
    const int r16  = lane & 15;

    const int row0 = blockIdx.y * 128;   // M origin
    const int col0 = blockIdx.x * 128;   // N origin
    const int m_off = (wave >> 1) * 64;  // wave sub-tile in M
    const int n_off = (wave & 1) * 64;   // wave sub-tile in N

    // Staging map (per BK=32 half): thread t covers tile row j*64 + t/4,
    // cols (t%4)*8 .. +8 (16 B); LDS byte offset = j*4096 + t*16.
    const int sr = tid >> 2;        // 0..63
    const int sc = (tid & 3) * 8;   // 0,8,16,24

    const unsigned short* Ag0 = A  + (size_t)(row0 + sr)      * K_TOTAL + sc;
    const unsigned short* Ag1 = A  + (size_t)(row0 + 64 + sr) * K_TOTAL + sc;
    const unsigned short* Bg0 = Bm + (size_t)(col0 + sr)      * K_TOTAL + sc;
    const unsigned short* Bg1 = Bm + (size_t)(col0 + 64 + sr) * K_TOTAL + sc;

    // LDS staging bases (elems). half h adds h*4096 elems; row-block r adds
    // r*2048; wave adds wave*512 (the wave's 1 KB slice, lane*16 B implicit).
    unsigned short* AsW = As + wave * 512;
    unsigned short* BsW = Bs + wave * 512;

    // Fragment LDS elem offsets within a half (row stride 32 elems = 64 B).
    const int a_ofs = (m_off + r16) * 32 + quad * 8;
    const int b_ofs = (n_off + r16) * 32 + quad * 8;

    floatx4 acc[4][4] = {};

    for (int kt = 0; kt < K_TOTAL; kt += 64) {
        __syncthreads();                 // previous iter's readers done
        // half 0 (cols kt..kt+32)
        async16(Ag0 + kt,      AsW);
        async16(Ag1 + kt,      AsW + 2048);
        async16(Bg0 + kt,      BsW);
        async16(Bg1 + kt,      BsW + 2048);
        // half 1 (cols kt+32..kt+64)
        async16(Ag0 + kt + 32, AsW + 4096);
        async16(Ag1 + kt + 32, AsW + 4096 + 2048);
        async16(Bg0 + kt + 32, BsW + 4096);
        async16(Bg1 + kt + 32, BsW + 4096 + 2048);
        __syncthreads();                 // drain vmcnt(0) once per 64 K

#pragma unroll
        for (int h = 0; h < 2; ++h) {
            bf16x8 a[4], b[4];
#pragma unroll
            for (int i = 0; i < 4; ++i)
                a[i] = *(const bf16x8*)(As + h * 4096 + a_ofs + i * (16 * 32));
#pragma unroll
            for (int i = 0; i < 4; ++i)
                b[i] = *(const bf16x8*)(Bs + h * 4096 + b_ofs + i * (16 * 32));

#pragma unroll
            for (int mi = 0; mi < 4; ++mi)
#pragma unroll
                for (int ni = 0; ni < 4; ++ni)
                    acc[mi][ni] = __builtin_amdgcn_mfma_f32_16x16x32_bf16(
                        a[mi], b[ni], acc[mi][ni], 0, 0, 0);
        }
    }

    // Epilogue. C/D layout (m89/m91-verified): col = lane&15, row = quad*4 + reg.
#pragma unroll
    for (int mi = 0; mi < 4; ++mi) {
#pragma unroll
        for (int ni = 0; ni < 4; ++ni) {
            const int r = row0 + m_off + mi * 16 + quad * 4;
            const int c = col0 + n_off + ni * 16 + r16;
#pragma unroll
            for (int i = 0; i < 4; ++i)
                C[(size_t)(r + i) * N_TOTAL + c] = acc[mi][ni][i];
        }
    }
}

// ---------------------------------------------------------------------------
extern "C" void kernel_launch(void* const* d_in, const int* in_sizes, int n_in,
                              void* d_out, int out_size, void* d_ws, size_t ws_size,
                              hipStream_t stream) {
    const float* x      = (const float*)d_in[0];   // [4,2048,4096] fp32
    const int*   packed = (const int*)d_in[1];     // [4096,2048] int32
    const float* scales = (const float*)d_in[2];   // [4096,1] fp32
    const float* ortho  = (const float*)d_in[3];   // [4096,4096] fp32
    float*       out    = (float*)d_out;           // [4,2048,4096] fp32

    // Workspace layout: Xb (bf16, 64 MB) | Wb (bf16, 32 MB) = 96 MB total
    unsigned short* Xb = (unsigned short*)d_ws;
    unsigned short* Wb = (unsigned short*)((char*)d_ws + (size_t)M_TOTAL * K_TOTAL * 2);

    prep_kernel<<<CVT_BLOCKS + DEQ_BLOCKS, 256, 0, stream>>>(x, packed, scales, ortho, Xb, Wb);

    dim3 grid(N_TOTAL / 128, M_TOTAL / 128);  // (32, 64) = 2048 blocks
    gemm_bt_kernel<<<grid, 256, 0, stream>>>(Xb, Wb, out);
}

// Round 3
// 634.088 us; speedup vs baseline: 1.1325x; 1.0068x over previous
//
#include <hip/hip_runtime.h>
#include <stdint.h>

// ---------------------------------------------------------------------------
// OrthoLinear: out[b,s,o] = sum_k x[b,s,k] * (dequant(base_packed,scales)[o,k]
//                                             + w_ortho[o,k])
// M = B*S = 8192, N = OUT = 4096, K = IN = 4096, fp32 in/out.
// R3: XOR bank-swizzle of 16B chunks in the LDS tiles. Staging permutes the
// *global source* per lane (global_load_lds dest is fixed at base+lane*16);
// fragment reads apply the same XOR. Kills the measured 3.36e7
// SQ_LDS_BANK_CONFLICT (~14% of GEMM cycles).
// ---------------------------------------------------------------------------

#define M_TOTAL 8192
#define N_TOTAL 4096
#define K_TOTAL 4096

typedef __attribute__((ext_vector_type(8)))  __bf16          bf16x8;   // MFMA A/B frag (4 VGPRs)
typedef __attribute__((ext_vector_type(4)))  float           floatx4;  // MFMA C/D frag
typedef __attribute__((ext_vector_type(8)))  unsigned short  ushort8;
typedef __attribute__((ext_vector_type(4)))  float           f32x4;
typedef __attribute__((ext_vector_type(4)))  int             intx4;

// fp32 -> bf16 round-to-nearest-even (data has no NaN)
__device__ __forceinline__ unsigned short f2bf(float f) {
    union { float f; uint32_t u; } c; c.f = f;
    uint32_t u = c.u + 0x7FFFu + ((c.u >> 16) & 1u);
    return (unsigned short)(u >> 16);
}

// ---------------------------------------------------------------------------
// Merged prep: blocks [0, 16384) convert x fp32->bf16 (8 floats/thread);
// blocks [16384, 24576) dequant W: (nibble-8)*scale + ortho -> bf16.
// Branch is block-uniform -> no divergence inside a wave.
// ---------------------------------------------------------------------------
#define CVT_BLOCKS 16384
#define DEQ_BLOCKS 8192

__global__ __launch_bounds__(256) void prep_kernel(
    const float* __restrict__ x,        // [M, K] fp32
    const int*   __restrict__ packed,   // [N, K/2] nibble-packed
    const float* __restrict__ scales,   // [N]
    const float* __restrict__ ortho,    // [N, K] fp32
    unsigned short* __restrict__ xb,    // [M, K] bf16 out
    unsigned short* __restrict__ wb)    // [N, K] bf16 out
{
    const int blk = blockIdx.x;
    if (blk < CVT_BLOCKS) {
        const size_t t = (size_t)blk * 256 + threadIdx.x;
        const f32x4* xv = (const f32x4*)x;
        f32x4 v0 = xv[2 * t];
        f32x4 v1 = xv[2 * t + 1];
        ushort8 r;
        r[0] = f2bf(v0[0]); r[1] = f2bf(v0[1]); r[2] = f2bf(v0[2]); r[3] = f2bf(v0[3]);
        r[4] = f2bf(v1[0]); r[5] = f2bf(v1[1]); r[6] = f2bf(v1[2]); r[7] = f2bf(v1[3]);
        ((ushort8*)xb)[t] = r;
    } else {
        const int t  = (blk - CVT_BLOCKS) * 256 + threadIdx.x;  // 0 .. N*(K/2)/4
        const int o  = t >> 9;                                  // 512 threads/row
        const int jp = (t & 511) << 2;                          // packed col base
        intx4 p = *(const intx4*)(packed + (size_t)o * (K_TOTAL / 2) + jp);
        const float s = scales[o];
        const size_t base = (size_t)o * K_TOTAL + (size_t)jp * 2;
        f32x4 g0 = *(const f32x4*)(ortho + base);
        f32x4 g1 = *(const f32x4*)(ortho + base + 4);
        float g[8] = { g0[0], g0[1], g0[2], g0[3], g1[0], g1[1], g1[2], g1[3] };
        ushort8 r;
#pragma unroll
        for (int i = 0; i < 4; ++i) {
            int pi = p[i];
            float lo = (float)((pi & 0xF) - 8) * s + g[2 * i];
            float hi = (float)(((pi >> 4) & 0xF) - 8) * s + g[2 * i + 1];
            r[2 * i]     = f2bf(lo);
            r[2 * i + 1] = f2bf(hi);
        }
        *(ushort8*)(wb + base) = r;
    }
}

// ---------------------------------------------------------------------------
// GEMM: C[M,N] = A[M,K](bf16) @ B[N,K](bf16)^T, fp32 accumulate.
// 128x128 block tile, BK=64 (two BK=32 halves per barrier pair), 256 threads
// = 4 waves (2x2 of 64x64), 4x4 mfma_f32_16x16x32_bf16 per k-step.
// LDS halves are [128 rows][4 chunks of 16B]; chunk c of row r is stored at
// chunk slot c ^ ((r>>1)&3)  (XOR bank swizzle, 2-way residual = free).
// ---------------------------------------------------------------------------
__device__ __forceinline__ void async16(const void* g, void* l) {
    __builtin_amdgcn_global_load_lds(
        (__attribute__((address_space(1))) void*)(g),
        (__attribute__((address_space(3))) void*)(l),
        16, 0, 0);
}

__global__ __launch_bounds__(256) void gemm_bt_kernel(
    const unsigned short* __restrict__ A,   // [M,K] bf16
    const unsigned short* __restrict__ Bm,  // [N,K] bf16
    float* __restrict__ C)                  // [M,N] fp32
{
    // 2 halves x 128 rows x 32 cols each = 8192 elems (16 KB) per matrix.
    __shared__ __attribute__((aligned(16))) unsigned short As[2 * 128 * 32];
    __shared__ __attribute__((aligned(16))) unsigned short Bs[2 * 128 * 32];

    const int tid  = threadIdx.x;
    const int wave = tid >> 6;
    const int lane = tid & 63;
    const int quad = lane >> 4;
    const int r16  = lane & 15;

    const int row0 = blockIdx.y * 128;   // M origin
    const int col0 = blockIdx.x * 128;   // N origin
    const int m_off = (wave >> 1) * 64;  // wave sub-tile in M
    const int n_off = (wave & 1) * 64;   // wave sub-tile in N

    // Staging map (per BK=32 half): thread t covers tile row j*64 + t/4.
    // LDS dest is fixed (byte offset t*16 within the half); the global source
    // chunk is XOR-swizzled: ct = (t&3) ^ ((row>>1)&3), row parity bits of the
    // row within the 128-row tile ((64+r)>>1 ≡ r>>1 mod 4, so both 64-row
    // blocks use the same lane formula).
    const int sr = tid >> 2;                               // 0..63 row in block
    const int ct = (tid & 3) ^ ((tid >> 3) & 3);           // swizzled chunk
    const int sc = ct * 8;                                 // elem col

    const unsigned short* Ag0 = A  + (size_t)(row0 + sr)      * K_TOTAL + sc;
    const unsigned short* Ag1 = A  + (size_t)(row0 + 64 + sr) * K_TOTAL + sc;
    const unsigned short* Bg0 = Bm + (size_t)(col0 + sr)      * K_TOTAL + sc;
    const unsigned short* Bg1 = Bm + (size_t)(col0 + 64 + sr) * K_TOTAL + sc;

    // LDS staging bases (elems): wave's 1 KB slice; lane*16 B implicit.
    unsigned short* AsW = As + wave * 512;
    unsigned short* BsW = Bs + wave * 512;

    // Fragment LDS elem offsets within a half (row stride 32 elems = 64 B).
    // Chunk read back through the same XOR; mi*16 and m_off=64 are ≡0 mod the
    // swizzle period, so the lane's swizzle term is constant.
    const int swz   = (r16 >> 1) & 3;
    const int a_ofs = (m_off + r16) * 32 + (quad ^ swz) * 8;
    const int b_ofs = (n_off + r16) * 32 + (quad ^ swz) * 8;

    floatx4 acc[4][4] = {};

    for (int kt = 0; kt < K_TOTAL; kt += 64) {
        __syncthreads();                 // previous iter's readers done
        // half 0 (cols kt..kt+32)
        async16(Ag0 + kt,      AsW);
        async16(Ag1 + kt,      AsW + 2048);
        async16(Bg0 + kt,      BsW);
        async16(Bg1 + kt,      BsW + 2048);
        // half 1 (cols kt+32..kt+64)
        async16(Ag0 + kt + 32, AsW + 4096);
        async16(Ag1 + kt + 32, AsW + 4096 + 2048);
        async16(Bg0 + kt + 32, BsW + 4096);
        async16(Bg1 + kt + 32, BsW + 4096 + 2048);
        __syncthreads();                 // drain vmcnt(0) once per 64 K

#pragma unroll
        for (int h = 0; h < 2; ++h) {
            bf16x8 a[4], b[4];
#pragma unroll
            for (int i = 0; i < 4; ++i)
                a[i] = *(const bf16x8*)(As + h * 4096 + a_ofs + i * (16 * 32));
#pragma unroll
            for (int i = 0; i < 4; ++i)
                b[i] = *(const bf16x8*)(Bs + h * 4096 + b_ofs + i * (16 * 32));

#pragma unroll
            for (int mi = 0; mi < 4; ++mi)
#pragma unroll
                for (int ni = 0; ni < 4; ++ni)
                    acc[mi][ni] = __builtin_amdgcn_mfma_f32_16x16x32_bf16(
                        a[mi], b[ni], acc[mi][ni], 0, 0, 0);
        }
    }

    // Epilogue. C/D layout (m89/m91-verified): col = lane&15, row = quad*4 + reg.
#pragma unroll
    for (int mi = 0; mi < 4; ++mi) {
#pragma unroll
        for (int ni = 0; ni < 4; ++ni) {
            const int r = row0 + m_off + mi * 16 + quad * 4;
            const int c = col0 + n_off + ni * 16 + r16;
#pragma unroll
            for (int i = 0; i < 4; ++i)
                C[(size_t)(r + i) * N_TOTAL + c] = acc[mi][ni][i];
        }
    }
}

// ---------------------------------------------------------------------------
extern "C" void kernel_launch(void* const* d_in, const int* in_sizes, int n_in,
                              void* d_out, int out_size, void* d_ws, size_t ws_size,
                              hipStream_t stream) {
    const float* x      = (const float*)d_in[0];   // [4,2048,4096] fp32
    const int*   packed = (const int*)d_in[1];     // [4096,2048] int32
    const float* scales = (const float*)d_in[2];   // [4096,1] fp32
    const float* ortho  = (const float*)d_in[3];   // [4096,4096] fp32
    float*       out    = (float*)d_out;           // [4,2048,4096] fp32

    // Workspace layout: Xb (bf16, 64 MB) | Wb (bf16, 32 MB) = 96 MB total
    unsigned short* Xb = (unsigned short*)d_ws;
    unsigned short* Wb = (unsigned short*)((char*)d_ws + (size_t)M_TOTAL * K_TOTAL * 2);

    prep_kernel<<<CVT_BLOCKS + DEQ_BLOCKS, 256, 0, stream>>>(x, packed, scales, ortho, Xb, Wb);

    dim3 grid(N_TOTAL / 128, M_TOTAL / 128);  // (32, 64) = 2048 blocks
    gemm_bt_kernel<<<grid, 256, 0, stream>>>(Xb, Wb, out);
}